// Round 1
// baseline (295.335 us; speedup 1.0000x reference)
//
#include <hip/hip_runtime.h>

// FiniteDifference: x[B=4,T=16,H=128,W=128,C=16] f32
// out = (dy along H, dx along W, dz along T), each = x[i+1]-x[i-1] (zero pad).
// Strides in floats: c:1, w:16, h:2048, t:262144, b:4194304.
// Each thread handles one float4 (4 channels) and produces all 3 outputs.

#define N_TOTAL (4 * 16 * 128 * 128 * 16)  // 16,777,216 elements
#define TOT4 (N_TOTAL / 4)                 // 4,194,304 float4s

__global__ __launch_bounds__(256) void fd3_kernel(
    const float4* __restrict__ x,
    float4* __restrict__ dy,   // d/dH
    float4* __restrict__ dx,   // d/dW
    float4* __restrict__ dz)   // d/dT
{
    // float4 strides: W: 16/4=4, H: 2048/4=512, T: 262144/4=65536
    constexpr int SW = 4;
    constexpr int SH = 512;
    constexpr int ST = 65536;

    int i = blockIdx.x * blockDim.x + threadIdx.x;
    if (i >= TOT4) return;

    // decompose float4 index: [b(2)][t(4)][h(7)][w(7)][c4(2)]
    int w = (i >> 2) & 127;
    int h = (i >> 9) & 127;
    int t = (i >> 16) & 15;

    const float4 z = make_float4(0.f, 0.f, 0.f, 0.f);

    float4 wm = (w > 0)   ? x[i - SW] : z;
    float4 wp = (w < 127) ? x[i + SW] : z;
    float4 hm = (h > 0)   ? x[i - SH] : z;
    float4 hp = (h < 127) ? x[i + SH] : z;
    float4 tm = (t > 0)   ? x[i - ST] : z;
    float4 tp = (t < 15)  ? x[i + ST] : z;

    dy[i] = make_float4(hp.x - hm.x, hp.y - hm.y, hp.z - hm.z, hp.w - hm.w);
    dx[i] = make_float4(wp.x - wm.x, wp.y - wm.y, wp.z - wm.z, wp.w - wm.w);
    dz[i] = make_float4(tp.x - tm.x, tp.y - tm.y, tp.z - tm.z, tp.w - tm.w);
}

extern "C" void kernel_launch(void* const* d_in, const int* in_sizes, int n_in,
                              void* d_out, int out_size, void* d_ws, size_t ws_size,
                              hipStream_t stream) {
    const float4* x = (const float4*)d_in[0];
    float* out = (float*)d_out;
    float4* dy = (float4*)(out);                 // reference returns (dy, dx, dz)
    float4* dx = (float4*)(out + N_TOTAL);
    float4* dz = (float4*)(out + 2 * (size_t)N_TOTAL);

    const int threads = 256;
    const int blocks = (TOT4 + threads - 1) / threads;  // 16384
    fd3_kernel<<<blocks, threads, 0, stream>>>(x, dy, dx, dz);
}

// Round 3
// 251.244 us; speedup vs baseline: 1.1755x; 1.1755x over previous
//
#include <hip/hip_runtime.h>

// FiniteDifference: x[B=4,T=16,H=128,W=128,C=16] f32
// out = (dy along H, dx along W, dz along T), each = x[i+1]-x[i-1] (zero "same" pad).
// Strides in floats: c:1, w:16, h:2048, t:262144, b:4194304.
// Each thread handles one float4 (4 channels), produces all 3 outputs.
// Outputs are write-once -> non-temporal stores (keep L2 for x's stencil reuse).
// NOTE: __builtin_nontemporal_store needs a native clang vector type, not
// HIP's float4 class -> use ext_vector_type(4).

typedef float f32x4 __attribute__((ext_vector_type(4)));

#define N_TOTAL (4 * 16 * 128 * 128 * 16)  // 16,777,216 elements
#define TOT4 (N_TOTAL / 4)                 // 4,194,304 float4s (grid divides exactly)

__global__ __launch_bounds__(256) void fd3_kernel(
    const f32x4* __restrict__ x,
    f32x4* __restrict__ dy,   // d/dH
    f32x4* __restrict__ dx,   // d/dW
    f32x4* __restrict__ dz)   // d/dT
{
    // float4 strides: W: 4, H: 512, T: 65536
    constexpr int SW = 4;
    constexpr int SH = 512;
    constexpr int ST = 65536;

    const int i = blockIdx.x * blockDim.x + threadIdx.x;

    // decompose float4 index: [b(2)][t(4)][h(7)][w(7)][c4(2)]
    const int w = (i >> 2) & 127;
    const int h = (i >> 9) & 127;
    const int t = (i >> 16) & 15;

    const f32x4 z = (f32x4)(0.f);

    const f32x4 wm = (w > 0)   ? x[i - SW] : z;
    const f32x4 wp = (w < 127) ? x[i + SW] : z;
    const f32x4 hm = (h > 0)   ? x[i - SH] : z;
    const f32x4 hp = (h < 127) ? x[i + SH] : z;
    const f32x4 tm = (t > 0)   ? x[i - ST] : z;
    const f32x4 tp = (t < 15)  ? x[i + ST] : z;

    __builtin_nontemporal_store(hp - hm, &dy[i]);
    __builtin_nontemporal_store(wp - wm, &dx[i]);
    __builtin_nontemporal_store(tp - tm, &dz[i]);
}

extern "C" void kernel_launch(void* const* d_in, const int* in_sizes, int n_in,
                              void* d_out, int out_size, void* d_ws, size_t ws_size,
                              hipStream_t stream) {
    const f32x4* x = (const f32x4*)d_in[0];
    float* out = (float*)d_out;
    f32x4* dy = (f32x4*)(out);                 // reference returns (dy, dx, dz)
    f32x4* dx = (f32x4*)(out + N_TOTAL);
    f32x4* dz = (f32x4*)(out + 2 * (size_t)N_TOTAL);

    const int threads = 256;
    const int blocks = TOT4 / threads;  // 16384
    fd3_kernel<<<blocks, threads, 0, stream>>>(x, dy, dx, dz);
}